// Round 14
// baseline (520.934 us; speedup 1.0000x reference)
//
#include <hip/hip_runtime.h>
#include <stdint.h>

typedef __bf16 bf16_t;
typedef __bf16 bf16x8 __attribute__((ext_vector_type(8)));
typedef __bf16 bf16x4v __attribute__((ext_vector_type(4)));
typedef float f32x16 __attribute__((ext_vector_type(16)));

#define AS_GLOBAL __attribute__((address_space(1)))
#define AS_LDS    __attribute__((address_space(3)))

static constexpr int NN   = 8192;   // nodes
static constexpr int DIN  = 512;
static constexpr int DOUT = 512;
static constexpr int SPLITK = 4;    // 256x256 tile: 32m x 2n x 4kc = 256 blocks = 1/CU

// 16B async global->LDS copy (global_load_lds_dwordx4).
__device__ __forceinline__ void async_cp16(const bf16_t* g, bf16_t* l) {
  __builtin_amdgcn_global_load_lds((AS_GLOBAL unsigned int*)g,
                                   (AS_LDS unsigned int*)l, 16, 0, 0);
}

// ---------------------------------------------------------------------------
// K1: d[i]=rsqrt(rowsum+1); adjb=bf16(adj+I); dxb[i,:]=bf16(d[i]*x[i,:]);
//     rows<512 also convert W. (measured-good from R13)
// ---------------------------------------------------------------------------
__global__ __launch_bounds__(256) void k_rowsum_convert(
    const float* __restrict__ adj, const float* __restrict__ x,
    const float* __restrict__ W, bf16_t* __restrict__ adjb,
    bf16_t* __restrict__ dxb, bf16_t* __restrict__ Wb,
    float* __restrict__ d) {
  const int row = blockIdx.x;
  const int t = threadIdx.x;
  const float4* rf4 = (const float4*)(adj + (size_t)row * NN);
  bf16_t* outp = adjb + (size_t)row * NN;
  const int diagF4 = row >> 2;
  float sum = 0.f;
#pragma unroll
  for (int c = 0; c < 8; ++c) {
    int f4i = c * 256 + t;               // 2048 float4 per row
    float4 a = rf4[f4i];
    sum += a.x + a.y + a.z + a.w;
    bf16x4v o;
    o[0] = (bf16_t)a.x; o[1] = (bf16_t)a.y; o[2] = (bf16_t)a.z; o[3] = (bf16_t)a.w;
    if (f4i == diagF4) {                 // fold identity into the bf16 matrix
      int s = row & 3;
      float vv = s == 0 ? a.x : s == 1 ? a.y : s == 2 ? a.z : a.w;
      o[s] = (bf16_t)(vv + 1.0f);
    }
    *(bf16x4v*)(outp + f4i * 4) = o;
  }
#pragma unroll
  for (int off = 32; off > 0; off >>= 1) sum += __shfl_down(sum, off);
  __shared__ float red[4];
  if ((t & 63) == 0) red[t >> 6] = sum;
  __syncthreads();
  const float s = rsqrtf(red[0] + red[1] + red[2] + red[3] + 1.0f);  // +1 identity
  if (t == 0) d[row] = s;
  if (t < 128) {                         // dxb row: 128 float4 = 512 elems
    float4 v = *(const float4*)(x + (size_t)row * DIN + t * 4);
    bf16x4v o;
    o[0] = (bf16_t)(v.x * s); o[1] = (bf16_t)(v.y * s);
    o[2] = (bf16_t)(v.z * s); o[3] = (bf16_t)(v.w * s);
    *(bf16x4v*)(dxb + (size_t)row * DIN + t * 4) = o;
  } else if (t < 256 && row < DOUT) {    // Wb row (rows 0..511)
    int tt = t - 128;
    float4 v = *(const float4*)(W + (size_t)row * DIN + tt * 4);
    bf16x4v o;
    o[0] = (bf16_t)v.x; o[1] = (bf16_t)v.y; o[2] = (bf16_t)v.z; o[3] = (bf16_t)v.w;
    *(bf16x4v*)(Wb + (size_t)row * DIN + tt * 4) = o;
  }
}

// ---------------------------------------------------------------------------
// 128x128 GEMM core (verified R4 structure) -- used by k_gemmY only.
// ---------------------------------------------------------------------------
__device__ __forceinline__ void gemm_tile_128x128_db(
    const bf16_t* __restrict__ A, const bf16_t* __restrict__ B,
    int lda, int ldb, int m0, int n0, int kStart, int kEnd,
    bf16_t* As, bf16_t* Bs, f32x16 acc[2][2]) {
  const int t = threadIdx.x;
  const int lane = t & 63;
  const int wid = t >> 6;
  const int wm = wid >> 1, wn = wid & 1;
  const int l32 = lane & 31, half = lane >> 5;

  const int swz = (t & 7) ^ ((t >> 3) & 7);
  const bf16_t* gA = A + (size_t)(m0 + (t >> 3)) * lda + swz * 8 + kStart;
  const bf16_t* gB = B + (size_t)(n0 + (t >> 3)) * ldb + swz * 8 + kStart;
  const int xorc = lane & 7;
  const int nIter = (kEnd - kStart) >> 6;

#pragma unroll
  for (int i = 0; i < 4; ++i) {
    async_cp16(gA + (size_t)(i * 32) * lda, As + t * 8 + i * 2048);
    async_cp16(gB + (size_t)(i * 32) * ldb, Bs + t * 8 + i * 2048);
  }
  gA += 64; gB += 64;

  int cur = 0;
  for (int it = 0; it < nIter; ++it) {
    if (it + 1 < nIter) {
      const int nb = (cur ^ 1) * 8192;
#pragma unroll
      for (int i = 0; i < 4; ++i) {
        async_cp16(gA + (size_t)(i * 32) * lda, As + nb + t * 8 + i * 2048);
        async_cp16(gB + (size_t)(i * 32) * ldb, Bs + nb + t * 8 + i * 2048);
      }
      gA += 64; gB += 64;
      asm volatile("s_waitcnt vmcnt(8)" ::: "memory");
    } else {
      asm volatile("s_waitcnt vmcnt(0)" ::: "memory");
    }
    __builtin_amdgcn_s_barrier();

    const bf16_t* Ab = As + cur * 8192;
    const bf16_t* Bb = Bs + cur * 8192;
#pragma unroll
    for (int ks = 0; ks < 4; ++ks) {
      const int pchunk = ((ks * 2 + half) ^ xorc) * 8;
      bf16x8 av[2], bv[2];
#pragma unroll
      for (int f = 0; f < 2; ++f) {
        av[f] = *(const bf16x8*)(Ab + (wm * 64 + f * 32 + l32) * 64 + pchunk);
        bv[f] = *(const bf16x8*)(Bb + (wn * 64 + f * 32 + l32) * 64 + pchunk);
      }
#pragma unroll
      for (int fm = 0; fm < 2; ++fm)
#pragma unroll
        for (int fn = 0; fn < 2; ++fn)
          acc[fm][fn] = __builtin_amdgcn_mfma_f32_32x32x16_bf16(
              av[fm], bv[fn], acc[fm][fn], 0, 0, 0);
    }
    asm volatile("s_waitcnt lgkmcnt(0)" ::: "memory");
    __builtin_amdgcn_s_barrier();
    cur ^= 1;
  }
}

// ---------------------------------------------------------------------------
// K4: YT[j][i] = bf16( sum_k Wb[j,k] * dxb[i,k] )   (512 x 8192, K=512)
// ---------------------------------------------------------------------------
__global__ __launch_bounds__(256) void k_gemmY(
    const bf16_t* __restrict__ Wb, const bf16_t* __restrict__ dxb,
    bf16_t* __restrict__ YT) {
  __shared__ __align__(16) bf16_t As[2 * 128 * 64];
  __shared__ __align__(16) bf16_t Bs[2 * 128 * 64];
  f32x16 acc[2][2];
#pragma unroll
  for (int a = 0; a < 2; ++a)
#pragma unroll
    for (int b = 0; b < 2; ++b)
#pragma unroll
      for (int r = 0; r < 16; ++r) acc[a][b][r] = 0.f;

  const int m0 = blockIdx.x * 128, n0 = blockIdx.y * 128;  // m over j, n over i
  gemm_tile_128x128_db(Wb, dxb, DIN, DIN, m0, n0, 0, DIN, As, Bs, acc);

  const int t = threadIdx.x;
  const int lane = t & 63, wid = t >> 6;
  const int wm = wid >> 1, wn = wid & 1;
  const int l32 = lane & 31, half = lane >> 5;
#pragma unroll
  for (int fm = 0; fm < 2; ++fm)
#pragma unroll
    for (int fn = 0; fn < 2; ++fn) {
      int gc = n0 + wn * 64 + fn * 32 + l32;
#pragma unroll
      for (int reg = 0; reg < 16; ++reg) {
        int gr = m0 + wm * 64 + fm * 32 + (reg & 3) + 8 * (reg >> 2) + 4 * half;
        YT[(size_t)gr * NN + gc] = (bf16_t)acc[fm][fn][reg];
      }
    }
}

// ---------------------------------------------------------------------------
// K5: gemm1, 256x256 tile, BK=32, FOUR LDS buffers, 3 tiles in flight (R13
// change). Rationale: R13's 2-deep covered ~1 iter of compute vs ~900cy HBM
// latency, and drained the pipe each K-step. Now: stage tile u+3 each iter;
// end-of-iter vmcnt(8) waits only tile u+1 (12 loads stay in flight, never
// drained in main loop); ONE barrier/iter (same 2-per-64K density).
// Pipeline proof: iter u stages into buf[(u+3)&3]=buf[(u-1)&3], whose readers
// finished at iter u-1's lgkmcnt(0)+barrier. Reads of buf[u&3] are safe: own
// wave waited u's loads (vmcnt chain) at iter u-1's end, barrier propagates
// to all waves. asm "memory" clobber on every waitcnt pins ds_read ordering.
// BK=32 swizzle: 4 chunks/row, s(r)=(r>>1)&3; phys p holds global p^s(r);
// stage g=(t&3)^((t>>3)&3) pre-swizzled source; read phys q^((l32>>1)&3).
// Bank check: lanes 0..7 tile all 8 16B-slots of the 128B bank window ->
// same conflict floor as the verified BK=64 scheme. + T5 setprio on MFMA.
// ---------------------------------------------------------------------------
__global__ __launch_bounds__(512, 1) void k_gemm1(
    const bf16_t* __restrict__ adjb, const bf16_t* __restrict__ YT,
    float* __restrict__ part) {
  __shared__ __align__(16) bf16_t As[4 * 8192];   // 4 bufs x 16 KB = 64 KB
  __shared__ __align__(16) bf16_t Bs[4 * 8192];   // 64 KB
  f32x16 acc[4][2];
#pragma unroll
  for (int a = 0; a < 4; ++a)
#pragma unroll
    for (int b = 0; b < 2; ++b)
#pragma unroll
      for (int r = 0; r < 16; ++r) acc[a][b][r] = 0.f;

  const int lin = blockIdx.x;                 // [0,256)
  const int c = (lin & 7) * 32 + (lin >> 3);  // XCD-chunked, bijective
  const int n0 = (c & 1) * 256;
  const int m0 = ((c >> 1) & 31) * 256;
  const int kc = c >> 6;
  const int kStart = kc * (NN / SPLITK);      // 2048-wide K chunk
  // nIter = 2048/32 = 64 (constant)

  const int t = threadIdx.x;
  const int lane = t & 63;
  const int wid = t >> 6;
  const int wm = wid >> 2, wn = wid & 3;      // 2m x 4n waves
  const int l32 = lane & 31, half = lane >> 5;
  const int sread = (l32 >> 1) & 3;           // read-side chunk swizzle

  const int g = (t & 3) ^ ((t >> 3) & 3);     // pre-swizzled global chunk
  const bf16_t* gA = adjb + (size_t)(m0 + (t >> 2)) * NN + g * 8 + kStart;
  const bf16_t* gB = YT   + (size_t)(n0 + (t >> 2)) * NN + g * 8 + kStart;

  // stage one 256x32 A-tile + B-tile into buffer `buf` (4 loads/thread-wave)
  auto stage = [&](int buf, int kk) {
#pragma unroll
    for (int i = 0; i < 2; ++i) {           // rows 0..127, 128..255
      async_cp16(gA + (size_t)(i * 128) * NN + kk, As + buf * 8192 + i * 4096 + t * 8);
      async_cp16(gB + (size_t)(i * 128) * NN + kk, Bs + buf * 8192 + i * 4096 + t * 8);
    }
  };

  // prologue: 3 tiles in flight (12 loads); wait tile 0 (newest 8 remain)
  stage(0, 0); stage(1, 32); stage(2, 64);
  asm volatile("s_waitcnt vmcnt(8)" ::: "memory");
  __builtin_amdgcn_s_barrier();

  for (int u = 0; u < 64; ++u) {
    if (u + 3 < 64) stage((u + 3) & 3, (u + 3) * 32);

    const bf16_t* Ab = As + (u & 3) * 8192;
    const bf16_t* Bb = Bs + (u & 3) * 8192;
    __builtin_amdgcn_s_setprio(1);
#pragma unroll
    for (int ks = 0; ks < 2; ++ks) {        // 2 K-steps of 16
      const int q = ks * 2 + half;          // logical 16B chunk (k = q*8)
      const int pc = (q ^ sread) * 8;       // physical element offset
      bf16x8 av[4], bv[2];
#pragma unroll
      for (int f = 0; f < 4; ++f)
        av[f] = *(const bf16x8*)(Ab + (wm * 128 + f * 32 + l32) * 32 + pc);
#pragma unroll
      for (int f = 0; f < 2; ++f)
        bv[f] = *(const bf16x8*)(Bb + (wn * 64 + f * 32 + l32) * 32 + pc);
#pragma unroll
      for (int fm = 0; fm < 4; ++fm)
#pragma unroll
        for (int fn = 0; fn < 2; ++fn)
          acc[fm][fn] = __builtin_amdgcn_mfma_f32_32x32x16_bf16(
              av[fm], bv[fn], acc[fm][fn], 0, 0, 0);
    }
    __builtin_amdgcn_s_setprio(0);
    // own ds_reads done (buffer reuse safety) ...
    asm volatile("s_waitcnt lgkmcnt(0)" ::: "memory");
    // ... and tile u+1 landed (counted: tiles u+2,u+3 stay in flight)
    if (u < 61)       asm volatile("s_waitcnt vmcnt(8)" ::: "memory");
    else if (u == 61) asm volatile("s_waitcnt vmcnt(4)" ::: "memory");
    else              asm volatile("s_waitcnt vmcnt(0)" ::: "memory");
    __builtin_amdgcn_s_barrier();
  }

  float* outp = part + (size_t)kc * NN * DOUT;
#pragma unroll
  for (int fm = 0; fm < 4; ++fm)
#pragma unroll
    for (int fn = 0; fn < 2; ++fn) {
      int gc = n0 + wn * 64 + fn * 32 + l32;
#pragma unroll
      for (int reg = 0; reg < 16; ++reg) {
        int gr = m0 + wm * 128 + fm * 32 + (reg & 3) + 8 * (reg >> 2) + 4 * half;
        outp[(size_t)gr * DOUT + gc] = acc[fm][fn][reg];
      }
    }
}

// ---------------------------------------------------------------------------
// K6: out[i][j] = relu( d[i] * (sum of SPLITK partials) + b[j] ),  fp32 out.
// ---------------------------------------------------------------------------
__global__ __launch_bounds__(256) void k_out(
    const float* __restrict__ part, const float* __restrict__ d,
    const float* __restrict__ bias, float* __restrict__ outp) {
  int idx = blockIdx.x * 256 + threadIdx.x;   // float4 index
  int i = idx >> 7;                           // 128 f4 per row
  int j4 = idx & 127;
  float4 p = *(const float4*)(part + (size_t)idx * 4);
#pragma unroll
  for (int kc = 1; kc < SPLITK; ++kc) {
    float4 q = *(const float4*)(part + (size_t)kc * NN * DOUT + (size_t)idx * 4);
    p.x += q.x; p.y += q.y; p.z += q.z; p.w += q.w;
  }
  float4 bb = *(const float4*)(bias + j4 * 4);
  float di = d[i];
  float4 o;
  o.x = fmaxf(fmaf(di, p.x, bb.x), 0.f);
  o.y = fmaxf(fmaf(di, p.y, bb.y), 0.f);
  o.z = fmaxf(fmaf(di, p.z, bb.z), 0.f);
  o.w = fmaxf(fmaf(di, p.w, bb.w), 0.f);
  *(float4*)(outp + (size_t)idx * 4) = o;
}

// ---------------------------------------------------------------------------
// out = relu(d . ((A+I) @ ((d.x) @ W^T)) + b)   [row-scale commutes with @W^T]
// ---------------------------------------------------------------------------
extern "C" void kernel_launch(void* const* d_in, const int* in_sizes, int n_in,
                              void* d_out, int out_size, void* d_ws, size_t ws_size,
                              hipStream_t stream) {
  const float* x   = (const float*)d_in[0];   // (8192, 512)
  const float* adj = (const float*)d_in[1];   // (8192, 8192)
  const float* W   = (const float*)d_in[2];   // (512, 512) (out,in)
  const float* b   = (const float*)d_in[3];   // (512,)
  float* out = (float*)d_out;                 // (8192, 512) fp32

  char* ws = (char*)d_ws;
  bf16_t* adjb = (bf16_t*)(ws);                        // 134 MB (8192x8192 bf16, +I folded)
  float*  part = (float*)(ws + 134217728);             // SPLITK x 16 MB fp32 = 64 MB
  bf16_t* YT   = (bf16_t*)(ws + 201326592);            // 8 MB (512x8192 bf16)
  bf16_t* dxb  = (bf16_t*)(ws + 209715200);            // 8 MB (8192x512 bf16)
  bf16_t* Wb   = (bf16_t*)(ws + 218103808);            // 0.5 MB
  float*  dvec = (float*)(ws + 218628096);             // 32 KB

  k_rowsum_convert<<<NN, 256, 0, stream>>>(adj, x, W, adjb, dxb, Wb, dvec);
  k_gemmY<<<dim3(DOUT / 128, NN / 128), 256, 0, stream>>>(Wb, dxb, YT);
  k_gemm1<<<(NN / 256) * (DOUT / 256) * SPLITK, 512, 0, stream>>>(adjb, YT, part);
  k_out<<<(NN * DOUT) / 1024, 256, 0, stream>>>(part, dvec, b, out);
}